// Round 6
// baseline (97.889 us; speedup 1.0000x reference)
//
#include <hip/hip_runtime.h>

#define N_SPOTS 50000
#define N_NEIGH 32
#define N_PROG  128

#define BLOCK 256
#define WPB   4

#define MAX_BLOCKS    256
#define QUANT_BLOCKS  3125   // 800,000 threads * 8 elems
#define GATHER_BLOCKS 3125   // 16 spots/block
#define F32_BLOCKS    6250   // fallback

// ws layout
#define TAB_BYTES  ((size_t)N_SPOTS * 64)            // 3,200,000 (int4 rows, 64B)
#define BMAX_OFF   TAB_BYTES                         // 256 floats
#define GSLOT_OFF  (BMAX_OFF + 1024)
#define TICKET_OFF (GSLOT_OFF + 64)
#define PART_OFF   (TICKET_OFF + 64)
#define NEED_BYTES (PART_OFF + (size_t)GATHER_BLOCKS * 4)

#if __has_builtin(__builtin_amdgcn_udot8)
__device__ __forceinline__ int dot8(unsigned a, unsigned b) {
    return __builtin_amdgcn_udot8(a, b, 0, false);
}
#else
__device__ __forceinline__ int dot8(unsigned a, unsigned b) {
    int s = 0;
    #pragma unroll
    for (int d = 0; d < 8; ++d)
        s += (int)((a >> (4 * d)) & 0xFu) * (int)((b >> (4 * d)) & 0xFu);
    return s;
}
#endif

__device__ __forceinline__ unsigned q4(float x, float r) {
    unsigned v = (unsigned)__builtin_fmaf(x, r, 0.5f);
    return v > 15u ? 15u : v;
}

// Pass 1: global max of probs -> blockmax[256]; also zero the ticket.
__global__ __launch_bounds__(BLOCK) void max_kernel(
    const float* __restrict__ probs, float* __restrict__ blockmax,
    unsigned* __restrict__ ticket)
{
    const float4* p4 = reinterpret_cast<const float4*>(probs);
    float m = 0.0f;
    for (int i = blockIdx.x * BLOCK + threadIdx.x; i < (N_SPOTS * N_PROG / 4);
         i += MAX_BLOCKS * BLOCK) {
        const float4 v = p4[i];
        m = fmaxf(m, fmaxf(fmaxf(v.x, v.y), fmaxf(v.z, v.w)));
    }
    #pragma unroll
    for (int off = 32; off > 0; off >>= 1) m = fmaxf(m, __shfl_down(m, off, 64));
    __shared__ float s[WPB];
    if ((threadIdx.x & 63) == 0) s[threadIdx.x >> 6] = m;
    __syncthreads();
    if (threadIdx.x == 0) {
        blockmax[blockIdx.x] = fmaxf(fmaxf(s[0], s[1]), fmaxf(s[2], s[3]));
        if (blockIdx.x == 0) *ticket = 0u;
    }
}

// Pass 2: reduce blockmax -> G; quantize 8 elems/thread to int4 (global scale).
__global__ __launch_bounds__(BLOCK) void quant_kernel(
    const float* __restrict__ probs, const float* __restrict__ blockmax,
    unsigned* __restrict__ tab, float* __restrict__ gslot)
{
    __shared__ float smax[WPB];
    __shared__ float gsh;
    float m = blockmax[threadIdx.x];                 // BLOCK == MAX_BLOCKS == 256
    #pragma unroll
    for (int off = 32; off > 0; off >>= 1) m = fmaxf(m, __shfl_down(m, off, 64));
    if ((threadIdx.x & 63) == 0) smax[threadIdx.x >> 6] = m;
    __syncthreads();
    if (threadIdx.x == 0)
        gsh = fmaxf(fmaxf(smax[0], smax[1]), fmaxf(smax[2], smax[3]));
    __syncthreads();
    const float r = 15.0f / gsh;

    const int t = blockIdx.x * BLOCK + threadIdx.x;  // [0, 800000)
    const float* rp = probs + (size_t)t * 8;
    const float4 a = *reinterpret_cast<const float4*>(rp);
    const float4 b = *reinterpret_cast<const float4*>(rp + 4);
    unsigned q = q4(a.x, r);
    q |= q4(a.y, r) << 4;   q |= q4(a.z, r) << 8;   q |= q4(a.w, r) << 12;
    q |= q4(b.x, r) << 16;  q |= q4(b.y, r) << 20;
    q |= q4(b.z, r) << 24;  q |= q4(b.w, r) << 28;
    tab[t] = q;
    if (t == 0) gslot[0] = gsh;
}

// Pass 3: gather + bias-corrected distance + fused finalize (ticket).
// dist_q = step^2 * (Qi2 + Qj2 - 2*D); bias 128*step^2/6 subtracted per edge.
__global__ __launch_bounds__(BLOCK) void gather_kernel(
    const unsigned* __restrict__ tab,
    const float* __restrict__ w,
    const int*   __restrict__ idx,
    const float* __restrict__ gslot,
    float* __restrict__ partials,
    unsigned* __restrict__ ticket,
    float* __restrict__ out)
{
    const int lane  = threadIdx.x & 63;
    const int sub   = lane & 15;
    const int wib   = threadIdx.x >> 6;
    const int grp16 = threadIdx.x >> 4;
    const int spot  = blockIdx.x * 16 + grp16;

    const unsigned pown = tab[spot * 16 + sub];
    const int Qi2 = dot8(pown, pown);

    const int   base = spot * N_NEIGH + sub;
    const int   i0 = idx[base], i1 = idx[base + 16];
    const float w0 = w[base],   w1 = w[base + 16];

    float sw = w0 + w1;                               // sum of the 32 weights
    #pragma unroll
    for (int off = 1; off < 16; off <<= 1) sw += __shfl_xor(sw, off, 16);

    __shared__ int2 stage[16][N_NEIGH];               // same-wave produce/consume
    stage[grp16][sub]      = make_int2(i0, __float_as_int(w0));
    stage[grp16][sub + 16] = make_int2(i1, __float_as_int(w1));

    float acc2 = 0.0f;
    #pragma unroll
    for (int c = 0; c < 4; ++c) {
        unsigned q[8]; float wj[8];
        #pragma unroll
        for (int k = 0; k < 8; ++k) {                 // 8 row gathers in flight
            const int2 e = stage[grp16][c * 8 + k];
            wj[k] = __int_as_float(e.y);
            q[k]  = tab[e.x * 16 + sub];
        }
        #pragma unroll
        for (int k = 0; k < 8; ++k) {                 // 2 udot8 + int + fma
            const int D  = dot8(pown, q[k]);
            const int Q2 = dot8(q[k], q[k]);
            acc2 = fmaf(wj[k], (float)(Q2 - 2 * D), acc2);
        }
    }

    const float G    = gslot[0];
    const float step = G * (1.0f / 15.0f);
    // per-lane: sw*(Qi2_l - 4/3) + acc2  (16 lanes x 4/3 = 128/6 bias per spot)
    float contrib = fmaf(sw, (float)Qi2 - (4.0f / 3.0f), acc2) * (step * step);

    #pragma unroll
    for (int off = 32; off > 0; off >>= 1)
        contrib += __shfl_down(contrib, off, 64);

    __shared__ float sred[WPB];
    __shared__ bool  slast;
    if (lane == 0) sred[wib] = contrib;
    __syncthreads();
    if (threadIdx.x == 0) {
        partials[blockIdx.x] = sred[0] + sred[1] + sred[2] + sred[3];
        __threadfence();
        const unsigned old = atomicAdd(ticket, 1u);
        slast = (old == GATHER_BLOCKS - 1);
    }
    __syncthreads();
    if (slast) {                                      // last block finalizes
        __threadfence();
        float a = 0.0f;
        for (int i = threadIdx.x; i < GATHER_BLOCKS; i += BLOCK) a += partials[i];
        #pragma unroll
        for (int off = 32; off > 0; off >>= 1) a += __shfl_down(a, off, 64);
        if (lane == 0) sred[wib] = a;
        __syncthreads();
        if (threadIdx.x == 0)
            out[0] = (sred[0] + sred[1] + sred[2] + sred[3]) / (float)N_SPOTS;
    }
}

// ---- fallback f32 path (exact), used only if ws too small ----
__global__ __launch_bounds__(BLOCK) void gather_f32_kernel(
    const float* __restrict__ probs,
    const float* __restrict__ w,
    const int*   __restrict__ idx,
    float* __restrict__ partials)
{
    const int wib  = threadIdx.x >> 6;
    const int lane = threadIdx.x & 63;
    const int sub  = lane & 31;
    const int half = lane >> 5;
    const int wg   = blockIdx.x * WPB + wib;
    const int spot = (wg << 1) + half;

    const float4 p = *reinterpret_cast<const float4*>(
        probs + (size_t)spot * N_PROG + sub * 4);
    const int   my_idx = idx[spot * N_NEIGH + sub];
    const float my_w   = w  [spot * N_NEIGH + sub];

    float acc = 0.0f;
    #pragma unroll 8
    for (int j = 0; j < N_NEIGH; ++j) {
        const int   nb = __shfl(my_idx, j, 32);
        const float wj = __shfl(my_w,   j, 32);
        const float4 q = *reinterpret_cast<const float4*>(
            probs + (size_t)nb * N_PROG + sub * 4);
        const float dx = p.x - q.x, dy = p.y - q.y;
        const float dz = p.z - q.z, dw = p.w - q.w;
        float sq = dx * dx;
        sq = fmaf(dy, dy, sq); sq = fmaf(dz, dz, sq); sq = fmaf(dw, dw, sq);
        acc = fmaf(wj, sq, acc);
    }
    #pragma unroll
    for (int off = 32; off > 0; off >>= 1) acc += __shfl_down(acc, off, 64);
    __shared__ float s[WPB];
    if (lane == 0) s[wib] = acc;
    __syncthreads();
    if (threadIdx.x == 0) {
        float t = 0.0f;
        #pragma unroll
        for (int v = 0; v < WPB; ++v) t += s[v];
        partials[blockIdx.x] = t;
    }
}

__global__ __launch_bounds__(BLOCK) void finalize_kernel(
    const float* __restrict__ partials, int nparts, float* __restrict__ out)
{
    const int wave = threadIdx.x >> 6;
    const int lane = threadIdx.x & 63;
    float acc = 0.0f;
    for (int i = threadIdx.x; i < nparts; i += BLOCK) acc += partials[i];
    #pragma unroll
    for (int off = 32; off > 0; off >>= 1) acc += __shfl_down(acc, off, 64);
    __shared__ float s[WPB];
    if (lane == 0) s[wave] = acc;
    __syncthreads();
    if (threadIdx.x == 0) {
        float t = 0.0f;
        #pragma unroll
        for (int v = 0; v < WPB; ++v) t += s[v];
        out[0] = t / (float)N_SPOTS;
    }
}

extern "C" void kernel_launch(void* const* d_in, const int* in_sizes, int n_in,
                              void* d_out, int out_size, void* d_ws, size_t ws_size,
                              hipStream_t stream) {
    const float* probs = (const float*)d_in[0];   // [N_SPOTS, N_PROG] f32
    const float* w     = (const float*)d_in[1];   // [N_SPOTS, N_NEIGH] f32
    const int*   idx   = (const int*)  d_in[2];   // [N_SPOTS, N_NEIGH] i32
    float* out = (float*)d_out;

    if (ws_size >= NEED_BYTES) {
        unsigned* tab      = (unsigned*)d_ws;
        float*    blockmax = (float*)((char*)d_ws + BMAX_OFF);
        float*    gslot    = (float*)((char*)d_ws + GSLOT_OFF);
        unsigned* ticket   = (unsigned*)((char*)d_ws + TICKET_OFF);
        float*    partials = (float*)((char*)d_ws + PART_OFF);

        max_kernel   <<<MAX_BLOCKS,    BLOCK, 0, stream>>>(probs, blockmax, ticket);
        quant_kernel <<<QUANT_BLOCKS,  BLOCK, 0, stream>>>(probs, blockmax, tab, gslot);
        gather_kernel<<<GATHER_BLOCKS, BLOCK, 0, stream>>>(tab, w, idx, gslot,
                                                           partials, ticket, out);
    } else {
        float* partials = (float*)d_ws;
        gather_f32_kernel<<<F32_BLOCKS, BLOCK, 0, stream>>>(probs, w, idx, partials);
        finalize_kernel  <<<1,          BLOCK, 0, stream>>>(partials, F32_BLOCKS, out);
    }
}

// Round 7
// 35.087 us; speedup vs baseline: 2.7899x; 2.7899x over previous
//
#include <hip/hip_runtime.h>

#define N_SPOTS 50000
#define N_NEIGH 32
#define N_PROG  128

#define BLOCK 256
#define WPB   4

#define MAX_BLOCKS    256
#define QUANT_BLOCKS  3125   // 800,000 threads * 8 elems
#define GATHER_BLOCKS 3125   // 16 spots/block
#define F32_BLOCKS    6250   // fallback

// ws layout
#define TAB_BYTES  ((size_t)N_SPOTS * 64)            // 3,200,000 (int4 rows, 64B)
#define BMAX_OFF   TAB_BYTES                         // 256 floats
#define GSLOT_OFF  (BMAX_OFF + 1024)
#define PART_OFF   (GSLOT_OFF + 64)
#define NEED_BYTES (PART_OFF + (size_t)GATHER_BLOCKS * 4)

#if __has_builtin(__builtin_amdgcn_udot8)
__device__ __forceinline__ int dot8(unsigned a, unsigned b) {
    return __builtin_amdgcn_udot8(a, b, 0, false);
}
#else
__device__ __forceinline__ int dot8(unsigned a, unsigned b) {
    int s = 0;
    #pragma unroll
    for (int d = 0; d < 8; ++d)
        s += (int)((a >> (4 * d)) & 0xFu) * (int)((b >> (4 * d)) & 0xFu);
    return s;
}
#endif

__device__ __forceinline__ unsigned q4(float x, float r) {
    unsigned v = (unsigned)__builtin_fmaf(x, r, 0.5f);
    return v > 15u ? 15u : v;
}

// Pass 1: global max of probs -> blockmax[256].
__global__ __launch_bounds__(BLOCK) void max_kernel(
    const float* __restrict__ probs, float* __restrict__ blockmax)
{
    const float4* p4 = reinterpret_cast<const float4*>(probs);
    float m = 0.0f;
    for (int i = blockIdx.x * BLOCK + threadIdx.x; i < (N_SPOTS * N_PROG / 4);
         i += MAX_BLOCKS * BLOCK) {
        const float4 v = p4[i];
        m = fmaxf(m, fmaxf(fmaxf(v.x, v.y), fmaxf(v.z, v.w)));
    }
    #pragma unroll
    for (int off = 32; off > 0; off >>= 1) m = fmaxf(m, __shfl_down(m, off, 64));
    __shared__ float s[WPB];
    if ((threadIdx.x & 63) == 0) s[threadIdx.x >> 6] = m;
    __syncthreads();
    if (threadIdx.x == 0)
        blockmax[blockIdx.x] = fmaxf(fmaxf(s[0], s[1]), fmaxf(s[2], s[3]));
}

// Pass 2: reduce blockmax -> G; quantize 8 elems/thread to int4 (global scale).
__global__ __launch_bounds__(BLOCK) void quant_kernel(
    const float* __restrict__ probs, const float* __restrict__ blockmax,
    unsigned* __restrict__ tab, float* __restrict__ gslot)
{
    __shared__ float smax[WPB];
    __shared__ float gsh;
    float m = blockmax[threadIdx.x];                 // BLOCK == MAX_BLOCKS == 256
    #pragma unroll
    for (int off = 32; off > 0; off >>= 1) m = fmaxf(m, __shfl_down(m, off, 64));
    if ((threadIdx.x & 63) == 0) smax[threadIdx.x >> 6] = m;
    __syncthreads();
    if (threadIdx.x == 0)
        gsh = fmaxf(fmaxf(smax[0], smax[1]), fmaxf(smax[2], smax[3]));
    __syncthreads();
    const float r = 15.0f / gsh;

    const int t = blockIdx.x * BLOCK + threadIdx.x;  // [0, 800000)
    const float* rp = probs + (size_t)t * 8;
    const float4 a = *reinterpret_cast<const float4*>(rp);
    const float4 b = *reinterpret_cast<const float4*>(rp + 4);
    unsigned q = q4(a.x, r);
    q |= q4(a.y, r) << 4;   q |= q4(a.z, r) << 8;   q |= q4(a.w, r) << 12;
    q |= q4(b.x, r) << 16;  q |= q4(b.y, r) << 20;
    q |= q4(b.z, r) << 24;  q |= q4(b.w, r) << 28;
    tab[t] = q;
    if (t == 0) gslot[0] = gsh;
}

// Pass 3: gather + bias-corrected distance -> per-block partial.
// dist_q = step^2 * (Qi2 + Qj2 - 2*D); bias 128*step^2/6 subtracted per edge.
__global__ __launch_bounds__(BLOCK) void gather_kernel(
    const unsigned* __restrict__ tab,
    const float* __restrict__ w,
    const int*   __restrict__ idx,
    const float* __restrict__ gslot,
    float* __restrict__ partials)
{
    const int lane  = threadIdx.x & 63;
    const int sub   = lane & 15;
    const int wib   = threadIdx.x >> 6;
    const int grp16 = threadIdx.x >> 4;
    const int spot  = blockIdx.x * 16 + grp16;

    const unsigned pown = tab[spot * 16 + sub];
    const int Qi2 = dot8(pown, pown);

    const int   base = spot * N_NEIGH + sub;
    const int   i0 = idx[base], i1 = idx[base + 16];
    const float w0 = w[base],   w1 = w[base + 16];

    float sw = w0 + w1;                               // sum of the 32 weights
    #pragma unroll
    for (int off = 1; off < 16; off <<= 1) sw += __shfl_xor(sw, off, 16);

    // same-wave produce/consume; split arrays -> conflict-free b32 writes
    __shared__ int   stage_i[16][N_NEIGH];
    __shared__ float stage_w[16][N_NEIGH];
    stage_i[grp16][sub]      = i0;  stage_w[grp16][sub]      = w0;
    stage_i[grp16][sub + 16] = i1;  stage_w[grp16][sub + 16] = w1;

    float acc2 = 0.0f;
    #pragma unroll
    for (int c = 0; c < 4; ++c) {
        unsigned q[8]; float wj[8];
        #pragma unroll
        for (int k = 0; k < 8; ++k) {                 // 8 row gathers in flight
            const int nb = stage_i[grp16][c * 8 + k]; // broadcast reads
            wj[k] = stage_w[grp16][c * 8 + k];
            q[k]  = tab[nb * 16 + sub];
        }
        #pragma unroll
        for (int k = 0; k < 8; ++k) {                 // 2 udot8 + int + fma
            const int D  = dot8(pown, q[k]);
            const int Q2 = dot8(q[k], q[k]);
            acc2 = fmaf(wj[k], (float)(Q2 - 2 * D), acc2);
        }
    }

    const float G    = gslot[0];
    const float step = G * (1.0f / 15.0f);
    // per-lane: sw*(Qi2_l - 4/3) + acc2  (16 lanes x 4/3 = 128/6 bias per spot)
    float contrib = fmaf(sw, (float)Qi2 - (4.0f / 3.0f), acc2) * (step * step);

    #pragma unroll
    for (int off = 32; off > 0; off >>= 1)
        contrib += __shfl_down(contrib, off, 64);

    __shared__ float sred[WPB];
    if (lane == 0) sred[wib] = contrib;
    __syncthreads();
    if (threadIdx.x == 0)
        partials[blockIdx.x] = sred[0] + sred[1] + sred[2] + sred[3];
}

// ---- fallback f32 path (exact), used only if ws too small ----
__global__ __launch_bounds__(BLOCK) void gather_f32_kernel(
    const float* __restrict__ probs,
    const float* __restrict__ w,
    const int*   __restrict__ idx,
    float* __restrict__ partials)
{
    const int wib  = threadIdx.x >> 6;
    const int lane = threadIdx.x & 63;
    const int sub  = lane & 31;
    const int half = lane >> 5;
    const int wg   = blockIdx.x * WPB + wib;
    const int spot = (wg << 1) + half;

    const float4 p = *reinterpret_cast<const float4*>(
        probs + (size_t)spot * N_PROG + sub * 4);
    const int   my_idx = idx[spot * N_NEIGH + sub];
    const float my_w   = w  [spot * N_NEIGH + sub];

    float acc = 0.0f;
    #pragma unroll 8
    for (int j = 0; j < N_NEIGH; ++j) {
        const int   nb = __shfl(my_idx, j, 32);
        const float wj = __shfl(my_w,   j, 32);
        const float4 q = *reinterpret_cast<const float4*>(
            probs + (size_t)nb * N_PROG + sub * 4);
        const float dx = p.x - q.x, dy = p.y - q.y;
        const float dz = p.z - q.z, dw = p.w - q.w;
        float sq = dx * dx;
        sq = fmaf(dy, dy, sq); sq = fmaf(dz, dz, sq); sq = fmaf(dw, dw, sq);
        acc = fmaf(wj, sq, acc);
    }
    #pragma unroll
    for (int off = 32; off > 0; off >>= 1) acc += __shfl_down(acc, off, 64);
    __shared__ float s[WPB];
    if (lane == 0) s[wib] = acc;
    __syncthreads();
    if (threadIdx.x == 0) {
        float t = 0.0f;
        #pragma unroll
        for (int v = 0; v < WPB; ++v) t += s[v];
        partials[blockIdx.x] = t;
    }
}

__global__ __launch_bounds__(BLOCK) void finalize_kernel(
    const float* __restrict__ partials, int nparts, float* __restrict__ out)
{
    const int wave = threadIdx.x >> 6;
    const int lane = threadIdx.x & 63;
    float acc = 0.0f;
    for (int i = threadIdx.x; i < nparts; i += BLOCK) acc += partials[i];
    #pragma unroll
    for (int off = 32; off > 0; off >>= 1) acc += __shfl_down(acc, off, 64);
    __shared__ float s[WPB];
    if (lane == 0) s[wave] = acc;
    __syncthreads();
    if (threadIdx.x == 0) {
        float t = 0.0f;
        #pragma unroll
        for (int v = 0; v < WPB; ++v) t += s[v];
        out[0] = t / (float)N_SPOTS;
    }
}

extern "C" void kernel_launch(void* const* d_in, const int* in_sizes, int n_in,
                              void* d_out, int out_size, void* d_ws, size_t ws_size,
                              hipStream_t stream) {
    const float* probs = (const float*)d_in[0];   // [N_SPOTS, N_PROG] f32
    const float* w     = (const float*)d_in[1];   // [N_SPOTS, N_NEIGH] f32
    const int*   idx   = (const int*)  d_in[2];   // [N_SPOTS, N_NEIGH] i32
    float* out = (float*)d_out;

    if (ws_size >= NEED_BYTES) {
        unsigned* tab      = (unsigned*)d_ws;
        float*    blockmax = (float*)((char*)d_ws + BMAX_OFF);
        float*    gslot    = (float*)((char*)d_ws + GSLOT_OFF);
        float*    partials = (float*)((char*)d_ws + PART_OFF);

        max_kernel     <<<MAX_BLOCKS,    BLOCK, 0, stream>>>(probs, blockmax);
        quant_kernel   <<<QUANT_BLOCKS,  BLOCK, 0, stream>>>(probs, blockmax, tab, gslot);
        gather_kernel  <<<GATHER_BLOCKS, BLOCK, 0, stream>>>(tab, w, idx, gslot, partials);
        finalize_kernel<<<1,             BLOCK, 0, stream>>>(partials, GATHER_BLOCKS, out);
    } else {
        float* partials = (float*)d_ws;
        gather_f32_kernel<<<F32_BLOCKS, BLOCK, 0, stream>>>(probs, w, idx, partials);
        finalize_kernel  <<<1,          BLOCK, 0, stream>>>(partials, F32_BLOCKS, out);
    }
}

// Round 8
// 34.674 us; speedup vs baseline: 2.8231x; 1.0119x over previous
//
#include <hip/hip_runtime.h>

#define N_SPOTS 50000
#define N_NEIGH 32
#define N_PROG  128

#define BLOCK 256
#define WPB   4

#define MAX_BLOCKS    256
#define QUANT_BLOCKS  3125   // 800,000 threads * 8 elems
#define GATHER_BLOCKS 3125   // 16 spots/block
#define F32_BLOCKS    6250   // fallback

// ws layout
#define TAB_BYTES  ((size_t)N_SPOTS * 64)            // 3,200,000 (int4 rows, 64B)
#define BMAX_OFF   TAB_BYTES                         // 256 floats
#define GSLOT_OFF  (BMAX_OFF + 1024)
#define PART_OFF   (GSLOT_OFF + 64)
#define NEED_BYTES (PART_OFF + (size_t)GATHER_BLOCKS * 4)

#if __has_builtin(__builtin_amdgcn_udot8)
__device__ __forceinline__ int dot8(unsigned a, unsigned b) {
    return __builtin_amdgcn_udot8(a, b, 0, false);
}
#else
__device__ __forceinline__ int dot8(unsigned a, unsigned b) {
    int s = 0;
    #pragma unroll
    for (int d = 0; d < 8; ++d)
        s += (int)((a >> (4 * d)) & 0xFu) * (int)((b >> (4 * d)) & 0xFu);
    return s;
}
#endif

__device__ __forceinline__ unsigned q4(float x, float r) {
    unsigned v = (unsigned)__builtin_fmaf(x, r, 0.5f);
    return v > 15u ? 15u : v;
}

// Pass 1: global max of probs -> blockmax[256].
__global__ __launch_bounds__(BLOCK) void max_kernel(
    const float* __restrict__ probs, float* __restrict__ blockmax)
{
    const float4* p4 = reinterpret_cast<const float4*>(probs);
    float m = 0.0f;
    for (int i = blockIdx.x * BLOCK + threadIdx.x; i < (N_SPOTS * N_PROG / 4);
         i += MAX_BLOCKS * BLOCK) {
        const float4 v = p4[i];
        m = fmaxf(m, fmaxf(fmaxf(v.x, v.y), fmaxf(v.z, v.w)));
    }
    #pragma unroll
    for (int off = 32; off > 0; off >>= 1) m = fmaxf(m, __shfl_down(m, off, 64));
    __shared__ float s[WPB];
    if ((threadIdx.x & 63) == 0) s[threadIdx.x >> 6] = m;
    __syncthreads();
    if (threadIdx.x == 0)
        blockmax[blockIdx.x] = fmaxf(fmaxf(s[0], s[1]), fmaxf(s[2], s[3]));
}

// Pass 2: reduce blockmax -> G; quantize 8 elems/thread to int4 (global scale).
__global__ __launch_bounds__(BLOCK) void quant_kernel(
    const float* __restrict__ probs, const float* __restrict__ blockmax,
    unsigned* __restrict__ tab, float* __restrict__ gslot)
{
    __shared__ float smax[WPB];
    __shared__ float gsh;
    float m = blockmax[threadIdx.x];                 // BLOCK == MAX_BLOCKS == 256
    #pragma unroll
    for (int off = 32; off > 0; off >>= 1) m = fmaxf(m, __shfl_down(m, off, 64));
    if ((threadIdx.x & 63) == 0) smax[threadIdx.x >> 6] = m;
    __syncthreads();
    if (threadIdx.x == 0)
        gsh = fmaxf(fmaxf(smax[0], smax[1]), fmaxf(smax[2], smax[3]));
    __syncthreads();
    const float r = 15.0f / gsh;

    const int t = blockIdx.x * BLOCK + threadIdx.x;  // [0, 800000)
    const float* rp = probs + (size_t)t * 8;
    const float4 a = *reinterpret_cast<const float4*>(rp);
    const float4 b = *reinterpret_cast<const float4*>(rp + 4);
    unsigned q = q4(a.x, r);
    q |= q4(a.y, r) << 4;   q |= q4(a.z, r) << 8;   q |= q4(a.w, r) << 12;
    q |= q4(b.x, r) << 16;  q |= q4(b.y, r) << 20;
    q |= q4(b.z, r) << 24;  q |= q4(b.w, r) << 28;
    tab[t] = q;
    if (t == 0) gslot[0] = gsh;
}

// Pass 3: gather + bias-corrected distance -> per-block partial.
// dist_q = step^2 * (Qi2 + Qj2 - 2*D); bias 128*step^2/6 subtracted per edge.
// 16 gathers in flight per wave (latency hiding), 2 chunks.
__global__ __launch_bounds__(BLOCK) void gather_kernel(
    const unsigned* __restrict__ tab,
    const float* __restrict__ w,
    const int*   __restrict__ idx,
    const float* __restrict__ gslot,
    float* __restrict__ partials)
{
    const int lane  = threadIdx.x & 63;
    const int sub   = lane & 15;
    const int wib   = threadIdx.x >> 6;
    const int grp16 = threadIdx.x >> 4;
    const int spot  = blockIdx.x * 16 + grp16;

    const unsigned pown = tab[spot * 16 + sub];
    const int Qi2 = dot8(pown, pown);

    const int   base = spot * N_NEIGH + sub;
    const int   i0 = idx[base], i1 = idx[base + 16];
    const float w0 = w[base],   w1 = w[base + 16];

    float sw = w0 + w1;                               // sum of the 32 weights
    #pragma unroll
    for (int off = 1; off < 16; off <<= 1) sw += __shfl_xor(sw, off, 16);

    // same-wave produce/consume; split arrays -> conflict-free b32 writes
    __shared__ int   stage_i[16][N_NEIGH];
    __shared__ float stage_w[16][N_NEIGH];
    stage_i[grp16][sub]      = i0;  stage_w[grp16][sub]      = w0;
    stage_i[grp16][sub + 16] = i1;  stage_w[grp16][sub + 16] = w1;

    float acc2 = 0.0f;
    #pragma unroll
    for (int c = 0; c < 2; ++c) {
        unsigned q[16];
        #pragma unroll
        for (int k = 0; k < 16; ++k) {                // 16 row gathers in flight
            const int nb = stage_i[grp16][c * 16 + k];
            q[k] = tab[nb * 16 + sub];
        }
        #pragma unroll
        for (int k = 0; k < 16; ++k) {                // 2 udot8 + int + fma
            const float wj = stage_w[grp16][c * 16 + k];
            const int D  = dot8(pown, q[k]);
            const int Q2 = dot8(q[k], q[k]);
            acc2 = fmaf(wj, (float)(Q2 - 2 * D), acc2);
        }
    }

    const float G    = gslot[0];
    const float step = G * (1.0f / 15.0f);
    // per-lane: sw*(Qi2_l - 4/3) + acc2  (16 lanes x 4/3 = 128/6 bias per spot)
    float contrib = fmaf(sw, (float)Qi2 - (4.0f / 3.0f), acc2) * (step * step);

    #pragma unroll
    for (int off = 32; off > 0; off >>= 1)
        contrib += __shfl_down(contrib, off, 64);

    __shared__ float sred[WPB];
    if (lane == 0) sred[wib] = contrib;
    __syncthreads();
    if (threadIdx.x == 0)
        partials[blockIdx.x] = sred[0] + sred[1] + sred[2] + sred[3];
}

// ---- fallback f32 path (exact), used only if ws too small ----
__global__ __launch_bounds__(BLOCK) void gather_f32_kernel(
    const float* __restrict__ probs,
    const float* __restrict__ w,
    const int*   __restrict__ idx,
    float* __restrict__ partials)
{
    const int wib  = threadIdx.x >> 6;
    const int lane = threadIdx.x & 63;
    const int sub  = lane & 31;
    const int half = lane >> 5;
    const int wg   = blockIdx.x * WPB + wib;
    const int spot = (wg << 1) + half;

    const float4 p = *reinterpret_cast<const float4*>(
        probs + (size_t)spot * N_PROG + sub * 4);
    const int   my_idx = idx[spot * N_NEIGH + sub];
    const float my_w   = w  [spot * N_NEIGH + sub];

    float acc = 0.0f;
    #pragma unroll 8
    for (int j = 0; j < N_NEIGH; ++j) {
        const int   nb = __shfl(my_idx, j, 32);
        const float wj = __shfl(my_w,   j, 32);
        const float4 q = *reinterpret_cast<const float4*>(
            probs + (size_t)nb * N_PROG + sub * 4);
        const float dx = p.x - q.x, dy = p.y - q.y;
        const float dz = p.z - q.z, dw = p.w - q.w;
        float sq = dx * dx;
        sq = fmaf(dy, dy, sq); sq = fmaf(dz, dz, sq); sq = fmaf(dw, dw, sq);
        acc = fmaf(wj, sq, acc);
    }
    #pragma unroll
    for (int off = 32; off > 0; off >>= 1) acc += __shfl_down(acc, off, 64);
    __shared__ float s[WPB];
    if (lane == 0) s[wib] = acc;
    __syncthreads();
    if (threadIdx.x == 0) {
        float t = 0.0f;
        #pragma unroll
        for (int v = 0; v < WPB; ++v) t += s[v];
        partials[blockIdx.x] = t;
    }
}

__global__ __launch_bounds__(BLOCK) void finalize_kernel(
    const float* __restrict__ partials, int nparts, float* __restrict__ out)
{
    const int wave = threadIdx.x >> 6;
    const int lane = threadIdx.x & 63;
    float acc = 0.0f;
    for (int i = threadIdx.x; i < nparts; i += BLOCK) acc += partials[i];
    #pragma unroll
    for (int off = 32; off > 0; off >>= 1) acc += __shfl_down(acc, off, 64);
    __shared__ float s[WPB];
    if (lane == 0) s[wave] = acc;
    __syncthreads();
    if (threadIdx.x == 0) {
        float t = 0.0f;
        #pragma unroll
        for (int v = 0; v < WPB; ++v) t += s[v];
        out[0] = t / (float)N_SPOTS;
    }
}

extern "C" void kernel_launch(void* const* d_in, const int* in_sizes, int n_in,
                              void* d_out, int out_size, void* d_ws, size_t ws_size,
                              hipStream_t stream) {
    const float* probs = (const float*)d_in[0];   // [N_SPOTS, N_PROG] f32
    const float* w     = (const float*)d_in[1];   // [N_SPOTS, N_NEIGH] f32
    const int*   idx   = (const int*)  d_in[2];   // [N_SPOTS, N_NEIGH] i32
    float* out = (float*)d_out;

    if (ws_size >= NEED_BYTES) {
        unsigned* tab      = (unsigned*)d_ws;
        float*    blockmax = (float*)((char*)d_ws + BMAX_OFF);
        float*    gslot    = (float*)((char*)d_ws + GSLOT_OFF);
        float*    partials = (float*)((char*)d_ws + PART_OFF);

        max_kernel     <<<MAX_BLOCKS,    BLOCK, 0, stream>>>(probs, blockmax);
        quant_kernel   <<<QUANT_BLOCKS,  BLOCK, 0, stream>>>(probs, blockmax, tab, gslot);
        gather_kernel  <<<GATHER_BLOCKS, BLOCK, 0, stream>>>(tab, w, idx, gslot, partials);
        finalize_kernel<<<1,             BLOCK, 0, stream>>>(partials, GATHER_BLOCKS, out);
    } else {
        float* partials = (float*)d_ws;
        gather_f32_kernel<<<F32_BLOCKS, BLOCK, 0, stream>>>(probs, w, idx, partials);
        finalize_kernel  <<<1,          BLOCK, 0, stream>>>(partials, F32_BLOCKS, out);
    }
}